// Round 7
// baseline (137.263 us; speedup 1.0000x reference)
//
#include <hip/hip_runtime.h>

typedef float v2f __attribute__((ext_vector_type(2)));

namespace {

constexpr int Tn = 1000, Fn = 22, Hn = 10, Cn = 4;
constexpr int CHF   = 32 * Fn;          // 704 floats per 32-step x chunk
constexpr int RINGF = 2 * CHF;          // ring base (floats): x = [2][704]
constexpr int LDSF  = RINGF + 2 * 32 * 16;  // + ring [2 slots][32 rows][16]

__device__ __forceinline__ v2f mk2(float a, float b) { v2f r; r.x=a; r.y=b; return r; }
__device__ __forceinline__ v2f fma2(v2f a, v2f b, v2f c) { return __builtin_elementwise_fma(a,b,c); }
__device__ __forceinline__ float rlane(float v, int l) {
    return __uint_as_float(__builtin_amdgcn_readlane(__float_as_uint(v), l));
}
__device__ __forceinline__ void gld_lds4(const float* g, float* l) {
    __builtin_amdgcn_global_load_lds(
        (const __attribute__((address_space(1))) unsigned int*)g,
        (__attribute__((address_space(3))) unsigned int*)l, 4, 0, 0);
}
__device__ __forceinline__ void sfence() { __builtin_amdgcn_sched_barrier(0); }
__device__ __forceinline__ void lgkm0_bar() {
    asm volatile("s_waitcnt lgkmcnt(0)" ::: "memory");  // h1 writes visible; DMA stays in flight
    __builtin_amdgcn_s_barrier();
}

__global__ __launch_bounds__(128, 2) void rnn_pipe(
    const float* __restrict__ x,
    const float* __restrict__ w_ih0, const float* __restrict__ w_hh0,
    const float* __restrict__ b_ih0, const float* __restrict__ b_hh0,
    const float* __restrict__ w_ih1, const float* __restrict__ w_hh1,
    const float* __restrict__ b_ih1, const float* __restrict__ b_hh1,
    const float* __restrict__ w_lin, const float* __restrict__ b_lin,
    float* __restrict__ out)
{
    __shared__ __align__(16) float lds[LDSF];
    float* xch  = lds;            // [2][704] staged x chunks (A only)
    float* ring = lds + RINGF;    // [2][32][16] h1 ring, row stride 64 B

    const int tid  = threadIdx.x;
    const int wid  = tid >> 6;        // wave 0 = layer-1 producer, wave 1 = layer-2 consumer
    const int lane = tid & 63;
    const int b    = blockIdx.x;
    const float* __restrict__ xrow = x + (size_t)b * (Tn * Fn);

    if (wid == 0) {
        // ===================== WAVE A: layer-1 chain =====================
        const int half = lane >> 5;            // 0: even steps, 1: odd steps
        const int l31  = lane & 31;
        const int jz   = (l31 < Hn) ? l31 : 0;

        v2f wih0p[11];
        #pragma unroll
        for (int p = 0; p < 11; ++p)
            wih0p[p] = mk2(w_ih0[jz*Fn + 2*p], w_ih0[jz*Fn + 2*p + 1]);
        float wa[Hn];
        #pragma unroll
        for (int k = 0; k < Hn; ++k) wa[k] = w_hh0[jz*Hn + k];
        const v2f bz2 = mk2(b_ih0[jz] + b_hh0[jz], 0.f);

        // ds_write lane->slot map: valid lanes hit row floats 0..9, rest dump to 10/11
        const int jslotE = (lane < 10) ? lane : 10;
        const int jslotO = (lane >= 32 && lane < 42) ? (lane - 32) : 11;

        auto stage = [&](int c) {           // x chunk c -> xch[c&1]
            float* dst = xch + (c & 1) * CHF;
            const float* src = xrow + c * CHF;
            if (c < 31) {
                #pragma unroll
                for (int k = 0; k < 11; ++k) gld_lds4(src + k*64 + lane, dst + k*64);
            } else {                         // chunk 31: 176 valid floats
                gld_lds4(src + lane, dst);
                gld_lds4(src + 64 + lane, dst + 64);
                if (lane < 48) gld_lds4(src + 128 + lane, dst + 128);
            }
        };

        v2f xv0[11], xv1[11];
        float S1[Hn];
        #pragma unroll
        for (int k = 0; k < Hn; ++k) S1[k] = 0.f;

        auto zc = [&](const v2f* xp) -> float {   // z-pair via 11 pk-FMA
            v2f z = fma2(xp[0], wih0p[0], bz2);
            #pragma unroll
            for (int p = 1; p < 11; ++p) z = fma2(xp[p], wih0p[p], z);
            return z.x + z.y;
        };
        auto loadxv = [&](v2f* dst, const float* rp) {
            #pragma unroll
            for (int p = 0; p < 11; ++p) dst[p] = *(const v2f*)(rp + 2*p);
            sfence();
        };

        float zA, zB;
        auto aStep = [&](bool up, float z, float* wptr, int foff) {
            float a = fmaf(S1[0], wa[0], z);
            float c = S1[1]*wa[1];
            a = fmaf(S1[2],wa[2],a);  c = fmaf(S1[3],wa[3],c);
            a = fmaf(S1[4],wa[4],a);  c = fmaf(S1[5],wa[5],c);
            a = fmaf(S1[6],wa[6],a);  c = fmaf(S1[7],wa[7],c);
            a = fmaf(S1[8],wa[8],a);  c = fmaf(S1[9],wa[9],c);
            const float hn = fmaxf(a + c, 0.f);
            const int base = up ? 32 : 0;
            #pragma unroll
            for (int k = 0; k < Hn; ++k) S1[k] = rlane(hn, base + k);
            wptr[foff] = hn;                    // ds_write_b32, imm offset
        };
        // 4 steps t=4m..4m+3 (m = 8p+mm); writes ring rows 4mm..4mm+3
        auto aMacro = [&](const float* xb_t, const float* xb_n, int mm,
                          float* wE, float* wO, bool ld0, bool ld1, bool z1) {
            const float* l0 = (mm < 7) ? xb_t + (2*mm + 2)*44 : xb_n;
            const float* l1 = (mm < 7) ? xb_t + (2*mm + 3)*44 : xb_n + 44;
            if (ld0) loadxv(xv1, l0);
            aStep(false, zA, wE, mm*64);
            zB = zc(xv0);
            aStep(true,  zA, wO, mm*64 + 16);
            if (ld1) loadxv(xv0, l1);
            aStep(false, zB, wE, mm*64 + 32);
            if (z1) zA = zc(xv1);
            aStep(true,  zB, wO, mm*64 + 48);
        };

        // prologue: stage chunks 0,1; x pairs 0,1 direct from global
        stage(0); stage(1);
        {
            v2f xd[11];
            const float* r01 = xrow + half * Fn;
            #pragma unroll
            for (int p = 0; p < 11; ++p) xd[p] = *(const v2f*)(r01 + 2*p);
            const float* r23 = xrow + (2 + half) * Fn;
            #pragma unroll
            for (int p = 0; p < 11; ++p) xv0[p] = *(const v2f*)(r23 + 2*p);
            asm volatile("s_waitcnt vmcnt(0)" ::: "memory");
            zA = zc(xd);            // z(0)/z(1) in lanes 0-9 / 32-41
        }

        #pragma unroll 1
        for (int p = 0; p <= 32; ++p) {
            if (p <= 30) {                       // full phase: 32 steps
                const int xs = p & 1;
                const float* xb_t = xch + xs*CHF + half*22;
                const float* xb_n = xch + (xs^1)*CHF + half*22;
                float* wE = ring + xs*512 + jslotE;
                float* wO = ring + xs*512 + jslotO;
                #pragma unroll
                for (int mm = 0; mm < 7; ++mm)
                    aMacro(xb_t, xb_n, mm, wE, wO, true, true, true);
                // stage 2 chunks ahead; all reads of this slot already issued
                asm volatile("s_waitcnt vmcnt(0)" ::: "memory");
                if (p <= 29) stage(p + 2);
                aMacro(xb_t, xb_n, 7, wE, wO, true, true, true);
            } else if (p == 31) {                // last 8 steps (t=992..999)
                const float* xb_t = xch + CHF + half*22;   // slot 1
                const float* xb_n = xch + half*22;
                float* wE = ring + 512 + jslotE;
                float* wO = ring + 512 + jslotO;
                aMacro(xb_t, xb_n, 0, wE, wO, true, true, true);
                aMacro(xb_t, xb_n, 1, wE, wO, false, false, false);
            }
            lgkm0_bar();
        }
    } else {
        // ===================== WAVE B: layer-2 chain + head =====================
        const int j2 = (lane < Hn) ? lane : 0;
        v2f wih1p[5];
        #pragma unroll
        for (int p = 0; p < 5; ++p)
            wih1p[p] = mk2(w_ih1[j2*Hn + 2*p], w_ih1[j2*Hn + 2*p + 1]);
        float whh1r[Hn];
        #pragma unroll
        for (int k = 0; k < Hn; ++k) whh1r[k] = w_hh1[j2*Hn + k];
        const v2f b2v = mk2(b_ih1[j2] + b_hh1[j2], 0.f);
        const int jc = (lane < Cn) ? lane : 0;
        float wl[Hn];
        #pragma unroll
        for (int k = 0; k < Hn; ++k) wl[k] = w_lin[jc*Hn + k];
        const float blv = b_lin[jc];

        float S2[Hn];
        #pragma unroll
        for (int k = 0; k < Hn; ++k) S2[k] = 0.f;
        v2f hv0[5], hv1[5];

        auto bload = [&](v2f* d, const float* rp) {   // h1 row: 5 uniform b64 reads
            #pragma unroll
            for (int k = 0; k < 5; ++k) d[k] = *(const v2f*)(rp + 2*k);
            sfence();
        };
        auto bStep = [&](const v2f* hp) {
            v2f acc = fma2(hp[0], wih1p[0], b2v);
            acc = fma2(hp[1], wih1p[1], acc);
            acc = fma2(hp[2], wih1p[2], acc);
            acc = fma2(hp[3], wih1p[3], acc);
            acc = fma2(hp[4], wih1p[4], acc);
            float d = acc.x + acc.y;
            d = fmaf(S2[0],whh1r[0],d);  d = fmaf(S2[1],whh1r[1],d);
            d = fmaf(S2[2],whh1r[2],d);  d = fmaf(S2[3],whh1r[3],d);
            d = fmaf(S2[4],whh1r[4],d);  d = fmaf(S2[5],whh1r[5],d);
            d = fmaf(S2[6],whh1r[6],d);  d = fmaf(S2[7],whh1r[7],d);
            d = fmaf(S2[8],whh1r[8],d);  d = fmaf(S2[9],whh1r[9],d);
            const float hn = fmaxf(d, 0.f);
            #pragma unroll
            for (int k = 0; k < Hn; ++k) S2[k] = rlane(hn, k);
        };

        #pragma unroll 1
        for (int p = 0; p <= 32; ++p) {
            if (p >= 1) {                        // consume chunk p-1
                const float* rb = ring + ((p-1) & 1) * 512;
                bload(hv0, rb);
                if (p < 32) {
                    #pragma unroll
                    for (int s = 0; s < 32; ++s) {
                        v2f* cur = (s & 1) ? hv1 : hv0;
                        v2f* nxt = (s & 1) ? hv0 : hv1;
                        if (s + 1 < 32) bload(nxt, rb + (s+1)*16);
                        bStep(cur);
                    }
                } else {                         // last phase: 8 steps
                    #pragma unroll
                    for (int s = 0; s < 8; ++s) {
                        v2f* cur = (s & 1) ? hv1 : hv0;
                        v2f* nxt = (s & 1) ? hv0 : hv1;
                        if (s + 1 < 8) bload(nxt, rb + (s+1)*16);
                        bStep(cur);
                    }
                }
            }
            lgkm0_bar();
        }

        // head: out[b,:] = h2(999) @ w_lin.T + b_lin  (h2 already relu'd)
        float o = blv;
        #pragma unroll
        for (int k = 0; k < Hn; ++k) o = fmaf(S2[k], wl[k], o);
        if (lane < Cn) out[b * Cn + lane] = o;
    }
}

} // namespace

extern "C" void kernel_launch(void* const* d_in, const int* in_sizes, int n_in,
                              void* d_out, int out_size, void* d_ws, size_t ws_size,
                              hipStream_t stream) {
    const float* x     = (const float*)d_in[0];
    const float* w_ih0 = (const float*)d_in[1];
    const float* w_hh0 = (const float*)d_in[2];
    const float* b_ih0 = (const float*)d_in[3];
    const float* b_hh0 = (const float*)d_in[4];
    const float* w_ih1 = (const float*)d_in[5];
    const float* w_hh1 = (const float*)d_in[6];
    const float* b_ih1 = (const float*)d_in[7];
    const float* b_hh1 = (const float*)d_in[8];
    const float* w_lin = (const float*)d_in[9];
    const float* b_lin = (const float*)d_in[10];
    float* out = (float*)d_out;

    // one batch per 128-thread block (2 waves: L1 producer + L2 consumer)
    // 1024 blocks -> 2048 waves -> 2 waves per SIMD
    rnn_pipe<<<dim3(1024), dim3(128), 0, stream>>>(
        x, w_ih0, w_hh0, b_ih0, b_hh0,
        w_ih1, w_hh1, b_ih1, b_hh1, w_lin, b_lin, out);
}